// Round 2
// baseline (648.512 us; speedup 1.0000x reference)
//
#include <hip/hip_runtime.h>
#include <hip/hip_fp16.h>

#define MM 8192
#define NN 4096
#define KK 4096
#define BM 128
#define BN 128
#define BK 32

typedef __attribute__((ext_vector_type(8))) short bf16x8;
typedef __attribute__((ext_vector_type(4))) float floatx4;

typedef const __attribute__((address_space(1))) unsigned int* gptr_t;
typedef __attribute__((address_space(3))) unsigned int* lptr_t;

// round-to-nearest-even fp32 -> bf16 bits (valid for non-NaN inputs)
__device__ __forceinline__ unsigned short f2bf(float f) {
    unsigned u = __builtin_bit_cast(unsigned, f);
    u += 0x7FFFu + ((u >> 16) & 1u);
    return (unsigned short)(u >> 16);
}

// ---- Prepass 1: x fp32 -> bf16 (row-major M x K) ----
__global__ __launch_bounds__(256) void cvt_x_kernel(const float4* __restrict__ x4,
                                                    ushort4* __restrict__ o4, int n4) {
    int i = blockIdx.x * 256 + threadIdx.x;
    if (i >= n4) return;
    float4 v = x4[i];
    ushort4 o;
    o.x = f2bf(v.x); o.y = f2bf(v.y); o.z = f2bf(v.z); o.w = f2bf(v.w);
    o4[i] = o;
}

// ---- Prepass 2: w (K x N fp32) -> sign(fp16(w)) as bf16, TRANSPOSED to N x K ----
__global__ __launch_bounds__(256) void binz_wt_kernel(const float* __restrict__ w,
                                                      unsigned short* __restrict__ wt) {
    __shared__ unsigned short tile[64][66];  // +2 pad: transposed read conflict-free
    const int n0 = blockIdx.x * 64;
    const int k0 = blockIdx.y * 64;
    const int t  = threadIdx.x;
    const int c  = t & 63;         // n within tile on read, k within tile on write
    const int r0 = (t >> 6) * 16;
#pragma unroll
    for (int i = 0; i < 16; ++i) {
        int r = r0 + i;            // k within tile
        float f = w[(size_t)(k0 + r) * NN + n0 + c];
        float h = __half2float(__float2half(f));   // fp16 round-trip
        // sign(clip(h,-1,1)) == sign(h): exact bf16 bits for {-1,0,+1}
        unsigned short b = (h > 0.f) ? 0x3F80u : ((h < 0.f) ? 0xBF80u : 0u);
        tile[r][c] = b;
    }
    __syncthreads();
#pragma unroll
    for (int i = 0; i < 16; ++i) {
        int rr = r0 + i;           // n within tile
        wt[(size_t)(n0 + rr) * KK + k0 + c] = tile[c][rr];
    }
}

// ---- GEMM: C[M,N] = A[M,K](bf16) * Bt[N,K](bf16, already transposed) ----
__global__ __launch_bounds__(256) void gemm_bin_kernel(const unsigned short* __restrict__ A,
                                                       const unsigned short* __restrict__ Bt,
                                                       float* __restrict__ C) {
    // One LDS object: A tile [BM][BK] at 0 (8 KiB), B tile [BN][BK] at 8192 (8 KiB)
    __shared__ __align__(16) char lds[(BM + BN) * BK * 2];

    const int t    = threadIdx.x;
    const int lane = t & 63;
    const int wave = t >> 6;      // 4 waves
    const int wm   = wave >> 1;   // 0..1
    const int wn   = wave & 1;    // 0..1
    const int quad = lane >> 4;   // 0..3
    const int l15  = lane & 15;

    // UNIFORM wave id for the LDS-DMA base (SGPR): lane L then writes base + L*16,
    // which equals chunk (wave*64 + j*256 + L) -- exactly each lane's global chunk.
    const int wave_u = __builtin_amdgcn_readfirstlane(wave);

    const int bm = blockIdx.y * BM;
    const int bn = blockIdx.x * BN;

    const char* gA = (const char*)A;
    const char* gB = (const char*)Bt;
    const unsigned short* lA = (const unsigned short*)lds;
    const unsigned short* lB = (const unsigned short*)(lds + BM * BK * 2);
    __attribute__((address_space(3))) char* lds3 =
        (__attribute__((address_space(3))) char*)lds;

    floatx4 acc[4][4] = {};

    for (int k0 = 0; k0 < KK; k0 += BK) {
        // stage A and B tiles: 512 chunks of 16B each per matrix, 2 per thread
#pragma unroll
        for (int j = 0; j < 2; ++j) {
            const int c   = t + j * 256;          // per-lane chunk id (global addr)
            const int row = c >> 2;               // tile row (A: m, B: n)
            const int cw  = c & 3;                // 16B chunk within the 64B row
            const int cb  = wave_u * 64 + j * 256; // uniform chunk base for this wave
            __builtin_amdgcn_global_load_lds(
                (gptr_t)(gA + ((size_t)(bm + row) * KK + k0) * 2 + cw * 16),
                (lptr_t)(lds3 + cb * 16), 16, 0, 0);
            __builtin_amdgcn_global_load_lds(
                (gptr_t)(gB + ((size_t)(bn + row) * KK + k0) * 2 + cw * 16),
                (lptr_t)(lds3 + BM * BK * 2 + cb * 16), 16, 0, 0);
        }
        __syncthreads();   // compiler emits s_waitcnt vmcnt(0) + s_barrier (m97 structure)

        bf16x8 af[4], bf[4];
#pragma unroll
        for (int i = 0; i < 4; ++i) {
            int arow = wm * 64 + i * 16 + l15;
            af[i] = *(const bf16x8*)&lA[arow * BK + quad * 8];
            int brow = wn * 64 + i * 16 + l15;
            bf[i] = *(const bf16x8*)&lB[brow * BK + quad * 8];
        }
#pragma unroll
        for (int i = 0; i < 4; ++i)
#pragma unroll
            for (int j = 0; j < 4; ++j)
                acc[i][j] = __builtin_amdgcn_mfma_f32_16x16x32_bf16(af[i], bf[j], acc[i][j], 0, 0, 0);
        __syncthreads();
    }

    // epilogue: C/D layout col=lane&15, row=quad*4+reg [verified m89/m91]
#pragma unroll
    for (int i = 0; i < 4; ++i) {
        int rbase = bm + wm * 64 + i * 16 + quad * 4;
#pragma unroll
        for (int j = 0; j < 4; ++j) {
            int col = bn + wn * 64 + j * 16 + l15;
#pragma unroll
            for (int r = 0; r < 4; ++r)
                C[(size_t)(rbase + r) * NN + col] = acc[i][j][r];
        }
    }
}

// ---- Fallback (insurance if ws too small): correct but slow ----
__global__ __launch_bounds__(256) void fallback_kernel(const float* __restrict__ x,
                                                       const float* __restrict__ w,
                                                       float* __restrict__ out) {
    int n = blockIdx.x * 256 + threadIdx.x;
    int m = blockIdx.y;
    float s = 0.f;
    for (int k = 0; k < KK; ++k) {
        float h = __half2float(__float2half(w[(size_t)k * NN + n]));
        float b = (h > 0.f) ? 1.f : ((h < 0.f) ? -1.f : 0.f);
        s += x[(size_t)m * KK + k] * b;
    }
    out[(size_t)m * NN + n] = s;
}

extern "C" void kernel_launch(void* const* d_in, const int* in_sizes, int n_in,
                              void* d_out, int out_size, void* d_ws, size_t ws_size,
                              hipStream_t stream) {
    const float* x = (const float*)d_in[0];
    const float* w = (const float*)d_in[1];
    // hedge: identify x by its element count (x is 8192*4096, w is 4096*4096)
    if (n_in >= 2 && in_sizes[0] != MM * KK) {
        x = (const float*)d_in[1];
        w = (const float*)d_in[0];
    }
    float* out = (float*)d_out;

    const size_t xb_bytes = (size_t)MM * KK * 2;   // 64 MiB
    const size_t wt_bytes = (size_t)NN * KK * 2;   // 32 MiB

    if (ws_size >= xb_bytes + wt_bytes) {
        unsigned short* xb = (unsigned short*)d_ws;
        unsigned short* wt = (unsigned short*)((char*)d_ws + xb_bytes);

        int n4 = MM * KK / 4;
        cvt_x_kernel<<<(n4 + 255) / 256, 256, 0, stream>>>((const float4*)x, (ushort4*)xb, n4);
        binz_wt_kernel<<<dim3(NN / 64, KK / 64), 256, 0, stream>>>(w, wt);
        gemm_bin_kernel<<<dim3(NN / BN, MM / BM), 256, 0, stream>>>(xb, wt, out);
    } else {
        fallback_kernel<<<dim3(NN / 256, MM), 256, 0, stream>>>(x, w, out);
    }
}

// Round 3
// 585.121 us; speedup vs baseline: 1.1083x; 1.1083x over previous
//
#include <hip/hip_runtime.h>
#include <hip/hip_fp16.h>

#define MM 8192
#define NN 4096
#define KK 4096
#define BM 128
#define BN 128
#define BK 32

typedef __attribute__((ext_vector_type(8))) short bf16x8;
typedef __attribute__((ext_vector_type(16))) float floatx16;
typedef __attribute__((ext_vector_type(8))) unsigned short ushort8_t;

typedef const __attribute__((address_space(1))) unsigned int* gptr_t;
typedef __attribute__((address_space(3))) unsigned int* lptr_t;

// round-to-nearest-even fp32 -> bf16 bits (valid for non-NaN inputs)
__device__ __forceinline__ unsigned short f2bf(float f) {
    unsigned u = __builtin_bit_cast(unsigned, f);
    u += 0x7FFFu + ((u >> 16) & 1u);
    return (unsigned short)(u >> 16);
}

__device__ __forceinline__ unsigned short sign_bf16(float f) {
    // sign(clip(fp16(f),-1,1)) == sign(fp16(f)); fp16 rounds |f|<2^-25 to 0
    float h = __half2float(__float2half(f));
    return (h > 0.f) ? 0x3F80u : ((h < 0.f) ? 0xBF80u : 0u);
}

// ---- Prepass 1: x fp32 -> bf16 (row-major M x K), 16B loads / 8B stores ----
__global__ __launch_bounds__(256) void cvt_x_kernel(const float4* __restrict__ x4,
                                                    ushort4* __restrict__ o4, int n4) {
    int i = blockIdx.x * 256 + threadIdx.x;
    if (i >= n4) return;
    float4 v = x4[i];
    ushort4 o;
    o.x = f2bf(v.x); o.y = f2bf(v.y); o.z = f2bf(v.z); o.w = f2bf(v.w);
    o4[i] = o;
}

// ---- Prepass 2: w (K x N fp32) -> sign(fp16(w)) bf16, transposed to N x K ----
// 64(k) x 64(n) tile per block; 16B/lane global reads AND writes.
__global__ __launch_bounds__(256) void binz_wt_kernel(const float* __restrict__ w,
                                                      unsigned short* __restrict__ wt) {
    __shared__ unsigned short tileT[64][72];   // [n][k]; 144B row stride (16B-aligned)
    const int n0 = blockIdx.x * 64;
    const int k0 = blockIdx.y * 64;
    const int t  = threadIdx.x;

    // Phase 1: read 4 float4 per thread (rows of w), transpose into LDS
    {
        const int c4 = t & 15;          // float4 column (n/4)
        const int rb = t >> 4;          // 16 k-rows per iter
#pragma unroll
        for (int i = 0; i < 4; ++i) {
            int r = rb + i * 16;        // k within tile
            float4 v = *(const float4*)&w[(size_t)(k0 + r) * NN + n0 + c4 * 4];
            tileT[c4 * 4 + 0][r] = sign_bf16(v.x);
            tileT[c4 * 4 + 1][r] = sign_bf16(v.y);
            tileT[c4 * 4 + 2][r] = sign_bf16(v.z);
            tileT[c4 * 4 + 3][r] = sign_bf16(v.w);
        }
    }
    __syncthreads();
    // Phase 2: write 16B (8 k-contiguous ushorts) per thread
    {
        const int g  = t & 7;           // k-granule (8 ushorts)
        const int nb = t >> 3;          // 32 n-rows per iter
#pragma unroll
        for (int i = 0; i < 2; ++i) {
            int n = nb + i * 32;
            *(ushort8_t*)&wt[(size_t)(n0 + n) * KK + k0 + g * 8] =
                *(const ushort8_t*)&tileT[n][g * 8];
        }
    }
}

// ---- GEMM: C[M,N] = A[M,K](bf16) * Bt[N,K](bf16), 32x32x16 MFMA ----
__global__ __launch_bounds__(256) void gemm_bin_kernel(const unsigned short* __restrict__ A,
                                                       const unsigned short* __restrict__ Bt,
                                                       float* __restrict__ C) {
    // One LDS object: A tile [BM][BK] at 0 (8 KiB), B tile [BN][BK] at 8192 (8 KiB)
    __shared__ __align__(16) char lds[(BM + BN) * BK * 2];

    const int t    = threadIdx.x;
    const int lane = t & 63;
    const int wave = t >> 6;      // 4 waves
    const int wm   = wave >> 1;   // 0..1
    const int wn   = wave & 1;    // 0..1
    const int l31  = lane & 31;
    const int kh   = lane >> 5;   // K-half within a 16-wide K slice

    // UNIFORM wave id for the LDS-DMA base (SGPR): lane L writes base + L*16.
    const int wave_u = __builtin_amdgcn_readfirstlane(wave);

    const int bm = blockIdx.y * BM;
    const int bn = blockIdx.x * BN;

    const char* gA = (const char*)A;
    const char* gB = (const char*)Bt;
    const unsigned short* lA = (const unsigned short*)lds;
    const unsigned short* lB = (const unsigned short*)(lds + BM * BK * 2);
    __attribute__((address_space(3))) char* lds3 =
        (__attribute__((address_space(3))) char*)lds;

    floatx16 acc[2][2] = {};

    for (int k0 = 0; k0 < KK; k0 += BK) {
        // stage A and B tiles: 512 chunks of 16B each per matrix, 2 per thread
#pragma unroll
        for (int j = 0; j < 2; ++j) {
            const int c   = t + j * 256;           // per-lane chunk id (global addr)
            const int row = c >> 2;                // tile row (A: m, B: n)
            const int cw  = c & 3;                 // 16B chunk within the 64B row
            const int cb  = wave_u * 64 + j * 256; // uniform chunk base for this wave
            __builtin_amdgcn_global_load_lds(
                (gptr_t)(gA + ((size_t)(bm + row) * KK + k0) * 2 + cw * 16),
                (lptr_t)(lds3 + cb * 16), 16, 0, 0);
            __builtin_amdgcn_global_load_lds(
                (gptr_t)(gB + ((size_t)(bn + row) * KK + k0) * 2 + cw * 16),
                (lptr_t)(lds3 + BM * BK * 2 + cb * 16), 16, 0, 0);
        }
        __syncthreads();   // s_waitcnt vmcnt(0) + s_barrier (m97 structure)

#pragma unroll
        for (int s = 0; s < 2; ++s) {              // two K=16 slices of BK=32
            bf16x8 af[2], bf[2];
#pragma unroll
            for (int i = 0; i < 2; ++i) {
                int arow = wm * 64 + i * 32 + l31;
                af[i] = *(const bf16x8*)&lA[arow * BK + s * 16 + kh * 8];
                int brow = wn * 64 + i * 32 + l31;
                bf[i] = *(const bf16x8*)&lB[brow * BK + s * 16 + kh * 8];
            }
#pragma unroll
            for (int i = 0; i < 2; ++i)
#pragma unroll
                for (int j = 0; j < 2; ++j)
                    acc[i][j] = __builtin_amdgcn_mfma_f32_32x32x16_bf16(
                        af[i], bf[j], acc[i][j], 0, 0, 0);
        }
        __syncthreads();
    }

    // epilogue: C/D layout col=lane&31, row=(reg&3)+8*(reg>>2)+4*(lane>>5)
    // [HW-verified m74/m101]
#pragma unroll
    for (int i = 0; i < 2; ++i) {
        int rbase = bm + wm * 64 + i * 32 + 4 * kh;
#pragma unroll
        for (int j = 0; j < 2; ++j) {
            int col = bn + wn * 64 + j * 32 + l31;
#pragma unroll
            for (int r = 0; r < 16; ++r) {
                int row = rbase + (r & 3) + 8 * (r >> 2);
                C[(size_t)row * NN + col] = acc[i][j][r];
            }
        }
    }
}

// ---- Fallback (insurance if ws too small): correct but slow ----
__global__ __launch_bounds__(256) void fallback_kernel(const float* __restrict__ x,
                                                       const float* __restrict__ w,
                                                       float* __restrict__ out) {
    int n = blockIdx.x * 256 + threadIdx.x;
    int m = blockIdx.y;
    float s = 0.f;
    for (int k = 0; k < KK; ++k) {
        float h = __half2float(__float2half(w[(size_t)k * NN + n]));
        float b = (h > 0.f) ? 1.f : ((h < 0.f) ? -1.f : 0.f);
        s += x[(size_t)m * KK + k] * b;
    }
    out[(size_t)m * NN + n] = s;
}

extern "C" void kernel_launch(void* const* d_in, const int* in_sizes, int n_in,
                              void* d_out, int out_size, void* d_ws, size_t ws_size,
                              hipStream_t stream) {
    const float* x = (const float*)d_in[0];
    const float* w = (const float*)d_in[1];
    // hedge: identify x by its element count (x is 8192*4096, w is 4096*4096)
    if (n_in >= 2 && in_sizes[0] != MM * KK) {
        x = (const float*)d_in[1];
        w = (const float*)d_in[0];
    }
    float* out = (float*)d_out;

    const size_t xb_bytes = (size_t)MM * KK * 2;   // 64 MiB
    const size_t wt_bytes = (size_t)NN * KK * 2;   // 32 MiB

    if (ws_size >= xb_bytes + wt_bytes) {
        unsigned short* xb = (unsigned short*)d_ws;
        unsigned short* wt = (unsigned short*)((char*)d_ws + xb_bytes);

        int n4 = MM * KK / 4;
        cvt_x_kernel<<<(n4 + 255) / 256, 256, 0, stream>>>((const float4*)x, (ushort4*)xb, n4);
        binz_wt_kernel<<<dim3(NN / 64, KK / 64), 256, 0, stream>>>(w, wt);
        gemm_bin_kernel<<<dim3(NN / BN, MM / BM), 256, 0, stream>>>(xb, wt, out);
    } else {
        fallback_kernel<<<dim3(NN / 256, MM), 256, 0, stream>>>(x, w, out);
    }
}